// Round 11
// baseline (104.584 us; speedup 1.0000x reference)
//
#include <hip/hip_runtime.h>

// Fused 6-layer MLP, v12: linear-stream staging + v10 compute.
// Grid 256 x 1024 thr (16 waves, 1 block/CU). Block owns 256 consecutive rows,
// processed as 16 chunks x 16 rows (50,176B contiguous each).
//   Stage: global_load_lds (16B/lane, 49 rounds/chunk, rounds {w,w+16,w+32}
//          per wave, +48 on wave 0), double-buffered -> HBM sees ~4 linear
//          streams/CU instead of 256 strided ones.
//   Compute: v10 mapping from LDS: wave w = k-iters {w,w+16,w+32}(+48 on w15),
//          lanes = 16 rows x 4 subs, W1 bf16-pair LDS broadcast, v_dot2_f32_bf16.
//          x-read banks: (16r+4s) mod 32 -> uniform 8 dwords/bank (no pad).
//   Reduce: shfl_xor(1,2) over subs -> h1 partial [row][wave] in dbuf LDS;
//   epilogue for chunk c-1 runs on waves 0-3 (16 q-lanes/row: shfl_xor 1,2,4,8
//   across 16 wave-partials, tiny layers redundant, 19 stores split by q).
// LDS: x 2x50,176 + W1 18,816 + h1p 2x16,384 = 151,936 B (dynamic).

__device__ __forceinline__ float ftanh(float v) {
    float e = __expf(2.0f * v);
    return 1.0f - 2.0f / (e + 1.0f);
}

__device__ __forceinline__ uint32_t cvtpk(float lo, float hi) {
    uint32_t d;
    asm("v_cvt_pk_bf16_f32 %0, %1, %2" : "=v"(d) : "v"(lo), "v"(hi));
    return d;
}

__device__ __forceinline__ float dot2(uint32_t a, uint32_t b, float c) {
    float d;
    asm("v_dot2_f32_bf16 %0, %1, %2, %3" : "=v"(d) : "v"(a), "v"(b), "v"(c));
    return d;
}

__device__ __forceinline__ void gload16(const float* g, float* l) {
    __builtin_amdgcn_global_load_lds(
        (const __attribute__((address_space(1))) void*)g,
        (__attribute__((address_space(3))) void*)l,
        16, 0, 0);
}

__device__ __forceinline__ void mlp_tail(
        const float* hp, int row, int q, const float* __restrict__ b1,
        const float* __restrict__ W2, const float* __restrict__ b2,
        const float* __restrict__ W3, const float* __restrict__ b3,
        const float* __restrict__ W4, const float* __restrict__ b4,
        const float* __restrict__ W5, const float* __restrict__ b5,
        const float* __restrict__ W6, const float* __restrict__ b6,
        float* __restrict__ out)
{
    const float4* h4p = (const float4*)hp;
    float4 a0 = h4p[0], a1 = h4p[1], a2 = h4p[2];
    float h1[12] = {a0.x, a0.y, a0.z, a0.w, a1.x, a1.y, a1.z, a1.w,
                    a2.x, a2.y, a2.z, a2.w};
#pragma unroll
    for (int j = 0; j < 12; ++j) {           // sum 16 wave-partials (q-groups)
        float z = h1[j];
        z += __shfl_xor(z, 1);
        z += __shfl_xor(z, 2);
        z += __shfl_xor(z, 4);
        z += __shfl_xor(z, 8);
        h1[j] = ftanh(z + b1[j]);
    }

    float h2[10];
#pragma unroll
    for (int m = 0; m < 10; ++m) {
        float t = b2[m];
#pragma unroll
        for (int j = 0; j < 12; ++j) t += h1[j] * W2[j * 10 + m];
        h2[m] = ftanh(t);
    }
    float h3[8];
#pragma unroll
    for (int m = 0; m < 8; ++m) {
        float t = b3[m];
#pragma unroll
        for (int j = 0; j < 10; ++j) t += h2[j] * W3[j * 8 + m];
        h3[m] = ftanh(t);
    }
    float h4[6];
#pragma unroll
    for (int m = 0; m < 6; ++m) {
        float t = b4[m];
#pragma unroll
        for (int j = 0; j < 8; ++j) t += h3[j] * W4[j * 6 + m];
        h4[m] = ftanh(t);
    }
    float h5[4];
#pragma unroll
    for (int m = 0; m < 4; ++m) {
        float t = b5[m];
#pragma unroll
        for (int j = 0; j < 6; ++j) t += h4[j] * W5[j * 4 + m];
        h5[m] = ftanh(t);
    }
    float o[10];
#pragma unroll
    for (int m = 0; m < 10; ++m) {
        float t = b6[m];
#pragma unroll
        for (int j = 0; j < 4; ++j) t += h5[j] * W6[j * 10 + m];
        o[m] = t;   // logits
    }

    const size_t H1o = 655360, H2o = 1441792, H3o = 2097152, H4o = 2621440, H5o = 3014656;
    float2* po  = (float2*)(out +       (size_t)row * 10);
    float4* ph1 = (float4*)(out + H1o + (size_t)row * 12);
    float2* ph2 = (float2*)(out + H2o + (size_t)row * 10);
    float4* ph3 = (float4*)(out + H3o + (size_t)row * 8);
    float2* ph4 = (float2*)(out + H4o + (size_t)row * 6);
    float4* ph5 = (float4*)(out + H5o + (size_t)row * 4);

    switch (q) {
        case 0:  po[0]  = make_float2(o[0], o[1]);
                 ph4[1] = make_float2(h4[2], h4[3]); break;
        case 1:  po[1]  = make_float2(o[2], o[3]);
                 ph4[2] = make_float2(h4[4], h4[5]); break;
        case 2:  po[2]  = make_float2(o[4], o[5]);
                 ph5[0] = make_float4(h5[0], h5[1], h5[2], h5[3]); break;
        case 3:  po[3]  = make_float2(o[6], o[7]); break;
        case 4:  po[4]  = make_float2(o[8], o[9]); break;
        case 5:  ph1[0] = make_float4(h1[0], h1[1], h1[2],  h1[3]);  break;
        case 6:  ph1[1] = make_float4(h1[4], h1[5], h1[6],  h1[7]);  break;
        case 7:  ph1[2] = make_float4(h1[8], h1[9], h1[10], h1[11]); break;
        case 8:  ph2[0] = make_float2(h2[0], h2[1]); break;
        case 9:  ph2[1] = make_float2(h2[2], h2[3]); break;
        case 10: ph2[2] = make_float2(h2[4], h2[5]); break;
        case 11: ph2[3] = make_float2(h2[6], h2[7]); break;
        case 12: ph2[4] = make_float2(h2[8], h2[9]); break;
        case 13: ph3[0] = make_float4(h3[0], h3[1], h3[2], h3[3]); break;
        case 14: ph3[1] = make_float4(h3[4], h3[5], h3[6], h3[7]); break;
        default: ph4[0] = make_float2(h4[0], h4[1]); break;
    }
}

#define KITER(i)                                                          \
    {                                                                     \
        float4 xv = *(const float4*)(xb + (i) * 16 + s * 4);              \
        const uint4* wb = (const uint4*)(lw + (i) * 96 + s * 24);         \
        uint4 A0 = wb[0], A1 = wb[1], A2 = wb[2];                         \
        uint4 B0 = wb[3], B1 = wb[4], B2 = wb[5];                         \
        uint32_t xp0 = cvtpk(xv.x, xv.y);                                 \
        uint32_t xp1 = cvtpk(xv.z, xv.w);                                 \
        acc[0]  = dot2(xp0, A0.x, acc[0]);                                \
        acc[1]  = dot2(xp0, A0.y, acc[1]);                                \
        acc[2]  = dot2(xp0, A0.z, acc[2]);                                \
        acc[3]  = dot2(xp0, A0.w, acc[3]);                                \
        acc[4]  = dot2(xp0, A1.x, acc[4]);                                \
        acc[5]  = dot2(xp0, A1.y, acc[5]);                                \
        acc[6]  = dot2(xp0, A1.z, acc[6]);                                \
        acc[7]  = dot2(xp0, A1.w, acc[7]);                                \
        acc[8]  = dot2(xp0, A2.x, acc[8]);                                \
        acc[9]  = dot2(xp0, A2.y, acc[9]);                                \
        acc[10] = dot2(xp0, A2.z, acc[10]);                               \
        acc[11] = dot2(xp0, A2.w, acc[11]);                               \
        acc[0]  = dot2(xp1, B0.x, acc[0]);                                \
        acc[1]  = dot2(xp1, B0.y, acc[1]);                                \
        acc[2]  = dot2(xp1, B0.z, acc[2]);                                \
        acc[3]  = dot2(xp1, B0.w, acc[3]);                                \
        acc[4]  = dot2(xp1, B1.x, acc[4]);                                \
        acc[5]  = dot2(xp1, B1.y, acc[5]);                                \
        acc[6]  = dot2(xp1, B1.z, acc[6]);                                \
        acc[7]  = dot2(xp1, B1.w, acc[7]);                                \
        acc[8]  = dot2(xp1, B2.x, acc[8]);                                \
        acc[9]  = dot2(xp1, B2.y, acc[9]);                                \
        acc[10] = dot2(xp1, B2.z, acc[10]);                               \
        acc[11] = dot2(xp1, B2.w, acc[11]);                               \
    }

#define STAGE(gbase, lbase)                                               \
    {                                                                     \
        const float* g_ = (gbase);                                        \
        float* l_ = (lbase);                                              \
        gload16(g_ + (wave)      * 256 + lane * 4, l_ + (wave)      * 256); \
        gload16(g_ + (wave + 16) * 256 + lane * 4, l_ + (wave + 16) * 256); \
        gload16(g_ + (wave + 32) * 256 + lane * 4, l_ + (wave + 32) * 256); \
        if (wave == 0)                                                    \
            gload16(g_ + 48 * 256 + lane * 4, l_ + 48 * 256);             \
    }

__global__ __launch_bounds__(1024, 4)
void mlp_fused12(const float* __restrict__ x,
                 const float* __restrict__ W1, const float* __restrict__ b1,
                 const float* __restrict__ W2, const float* __restrict__ b2,
                 const float* __restrict__ W3, const float* __restrict__ b3,
                 const float* __restrict__ W4, const float* __restrict__ b4,
                 const float* __restrict__ W5, const float* __restrict__ b5,
                 const float* __restrict__ W6, const float* __restrict__ b6,
                 float* __restrict__ out)
{
    extern __shared__ float smem[];
    float*    const xbuf = smem;                        // [2][12544] floats
    uint32_t* const lw   = (uint32_t*)(smem + 25088);   // [392*12] bf16-pairs
    float*    const h1p  = smem + 29792;                // [2][16r][16w][16]

    const int tid  = threadIdx.x;
    const int wave = tid >> 6;
    const int lane = tid & 63;

    // ---- pack W1 -> LDS (bf16 k-pairs, v10 layout) ----
    for (int t = tid; t < 4704; t += 1024) {
        int p = t / 12, j = t - p * 12;
        lw[t] = cvtpk(W1[p * 24 + j], W1[p * 24 + 12 + j]);
    }

    const size_t row0 = (size_t)blockIdx.x << 8;        // 256 rows/block
    const float* xg   = x + row0 * 784;

    STAGE(xg, xbuf);                                    // chunk 0 -> buf 0

    const int r = lane >> 2;
    const int s = lane & 3;

    for (int c = 0; c < 16; ++c) {
        __syncthreads();      // drains stage(c) DMA; h1p[c&1] free; W1 ready

        if (c < 15) STAGE(xg + (size_t)(c + 1) * 12544, xbuf + ((c + 1) & 1) * 12544);

        {   // ---- compute chunk c ----
            const float* xb = xbuf + (c & 1) * 12544 + r * 784;
            float acc[12];
#pragma unroll
            for (int j = 0; j < 12; ++j) acc[j] = 0.f;

            KITER(wave);
            KITER(wave + 16);
            KITER(wave + 32);
            if (wave == 15) KITER(48);

#pragma unroll
            for (int j = 0; j < 12; ++j) {
                float z = acc[j];
                z += __shfl_xor(z, 1);
                z += __shfl_xor(z, 2);
                acc[j] = z;
            }
            if (s == 0) {
                float4* q4 = (float4*)(h1p + (c & 1) * 4096 + r * 256 + wave * 16);
                q4[0] = make_float4(acc[0], acc[1], acc[2],  acc[3]);
                q4[1] = make_float4(acc[4], acc[5], acc[6],  acc[7]);
                q4[2] = make_float4(acc[8], acc[9], acc[10], acc[11]);
            }
        }

        if (c > 0 && tid < 256) {           // ---- epilogue chunk c-1 ----
            const int rr = tid >> 4, q = tid & 15;
            mlp_tail(h1p + ((c - 1) & 1) * 4096 + rr * 256 + q * 16,
                     (int)(row0 + (c - 1) * 16 + rr), q,
                     b1, W2, b2, W3, b3, W4, b4, W5, b5, W6, b6, out);
        }
    }

    __syncthreads();
    if (tid < 256) {                         // ---- epilogue chunk 15 ----
        const int rr = tid >> 4, q = tid & 15;
        mlp_tail(h1p + (15 & 1) * 4096 + rr * 256 + q * 16,
                 (int)(row0 + 15 * 16 + rr), q,
                 b1, W2, b2, W3, b3, W4, b4, W5, b5, W6, b6, out);
    }
}

extern "C" void kernel_launch(void* const* d_in, const int* in_sizes, int n_in,
                              void* d_out, int out_size, void* d_ws, size_t ws_size,
                              hipStream_t stream) {
    (void)in_sizes; (void)n_in; (void)d_ws; (void)ws_size; (void)out_size;
    mlp_fused12<<<256, 1024, 151936, stream>>>(
        (const float*)d_in[0],
        (const float*)d_in[1],  (const float*)d_in[2],
        (const float*)d_in[3],  (const float*)d_in[4],
        (const float*)d_in[5],  (const float*)d_in[6],
        (const float*)d_in[7],  (const float*)d_in[8],
        (const float*)d_in[9],  (const float*)d_in[10],
        (const float*)d_in[11], (const float*)d_in[12],
        (float*)d_out);
}